// Round 7
// baseline (293.853 us; speedup 1.0000x reference)
//
#include <hip/hip_runtime.h>
#include <stdint.h>

// LinearAttention. R6: INSTRUMENTATION ROUND — identical R5 kernels;
// kernA launched 3x (idempotent) to measure kernA = (dur - 204)/2 and,
// if kernA >= ~97us, surface its rocprof counters past the poison-fills.
// Math: final[b,o,n] = sum_c M_b[o,c] x[b,c,n] + b_out[o]
//   M_b = W_out * blockdiag_h(ctx_h^T) * W_q
//   ctx[hd][e] = (1/Z[hd]) sum_c A[hd][c] Wv[32h+e][c]
//   A[hd][c]   = sum_n exp(k[hd,n]) x[c,n],  Z[hd] = sum_n exp(k[hd,n])
//   k[hd,n]    = sum_c Wk[hd][c] x[c,n]   (k ~ N(0,0.4^2): exp fp32-safe)

#define N_POS 81920   // 80*1024
#define NT    128     // positions per kernA tile
#define TILES 640     // tiles per batch

typedef short bf16x8 __attribute__((ext_vector_type(8)));
typedef float f32x4  __attribute__((ext_vector_type(4)));

__device__ __forceinline__ uint32_t packbf(float lo, float hi){
  uint32_t a = __float_as_uint(lo), b = __float_as_uint(hi);
  a = (a + 0x8000u) >> 16;
  b = (b + 0x8000u) & 0xffff0000u;
  return a | b;
}
__device__ __forceinline__ short bf16of(float v){
  return (short)((__float_as_uint(v) + 0x8000u) >> 16);
}

// ---------------------------------------------------------------------------
// kernA: per (batch, chunk): partial A[128][64], Z[128] via MFMA.
// 512 threads = 8 waves, tile = 128 pos. (identical to R5)
// ---------------------------------------------------------------------------
__global__ __launch_bounds__(512, 4) void kernA(
    const float* __restrict__ x, const float* __restrict__ w,
    float* __restrict__ pA, float* __restrict__ pZ, int nch, int tpc)
{
  __shared__ __align__(16) uint16_t xs_cp[64 * 136];   // [c][pos]
  __shared__ __align__(16) uint16_t xs_pc[128 * 72];   // [pos][c]
  __shared__ __align__(16) uint16_t es[128 * 136];     // [hd][pos]

  const int t  = threadIdx.x;
  const int w8 = t >> 6;     // wave 0..7
  const int l  = t & 63;
  const int lm = l & 15;
  const int lg = l >> 4;

  const int b  = blockIdx.x / nch;
  const int ch = blockIdx.x % nch;
  const float* xb = x + (size_t)b * 64 * N_POS;

  // staging roles
  const int rr  = t >> 3;        // xs_cp: c row 0..63
  const int pg  = t & 7;         // xs_cp: 16-pos group
  const int spp = t & 127;       // xs_pc: pos
  const int scg = t >> 7;        // xs_pc: c-group (16 c)

  // phase1 split: 2 pos-tiles x 4 ht per wave
  const int pth = w8 & 3;
  const int ht0 = (w8 >> 2) * 4;

  // Wk B-fragments for ht0..ht0+3 (w_qkv rows 128..255)
  bf16x8 wkf[4][2];
  #pragma unroll
  for (int i = 0; i < 4; ++i)
    #pragma unroll
    for (int kk = 0; kk < 2; ++kk){
      const float* wp = w + (size_t)(128 + 16*(ht0+i) + lm) * 64 + 32*kk + 8*lg;
      float4 w0 = *(const float4*)wp;
      float4 w1 = *(const float4*)(wp + 4);
      bf16x8 f;
      f[0]=bf16of(w0.x); f[1]=bf16of(w0.y); f[2]=bf16of(w0.z); f[3]=bf16of(w0.w);
      f[4]=bf16of(w1.x); f[5]=bf16of(w1.y); f[6]=bf16of(w1.z); f[7]=bf16of(w1.w);
      wkf[i][kk] = f;
    }

  bf16x8 ones;
  #pragma unroll
  for (int j = 0; j < 8; ++j) ones[j] = (short)0x3F80;   // bf16 1.0

  f32x4 acc[4], zac;
  zac = (f32x4){0.f,0.f,0.f,0.f};
  #pragma unroll
  for (int n = 0; n < 4; ++n) acc[n] = (f32x4){0.f,0.f,0.f,0.f};

  // prefetch tile 0
  float4 fa0, fa1, fa2, fa3;
  float v[16];
  {
    const int n0 = (ch * tpc) * NT;
    const float* ga = xb + (size_t)rr * N_POS + n0 + 16*pg;
    fa0 = *(const float4*)ga;       fa1 = *(const float4*)(ga + 4);
    fa2 = *(const float4*)(ga + 8); fa3 = *(const float4*)(ga + 12);
    const float* gb = xb + (size_t)(16*scg) * N_POS + n0 + spp;
    #pragma unroll
    for (int i = 0; i < 16; ++i) v[i] = gb[(size_t)i * N_POS];
  }

  for (int tile = 0; tile < tpc; ++tile){
    __syncthreads();   // prev phase2 done with xs_cp/es
    // write staged tile to LDS
    {
      uint4 u0, u1;
      u0.x = packbf(fa0.x,fa0.y); u0.y = packbf(fa0.z,fa0.w);
      u0.z = packbf(fa1.x,fa1.y); u0.w = packbf(fa1.z,fa1.w);
      u1.x = packbf(fa2.x,fa2.y); u1.y = packbf(fa2.z,fa2.w);
      u1.z = packbf(fa3.x,fa3.y); u1.w = packbf(fa3.z,fa3.w);
      *(uint4*)&xs_cp[rr*136 + 16*pg]     = u0;
      *(uint4*)&xs_cp[rr*136 + 16*pg + 8] = u1;
      uint4 p0, p1;
      p0.x = packbf(v[0],v[1]);   p0.y = packbf(v[2],v[3]);
      p0.z = packbf(v[4],v[5]);   p0.w = packbf(v[6],v[7]);
      p1.x = packbf(v[8],v[9]);   p1.y = packbf(v[10],v[11]);
      p1.z = packbf(v[12],v[13]); p1.w = packbf(v[14],v[15]);
      *(uint4*)&xs_pc[spp*72 + 16*scg]     = p0;
      *(uint4*)&xs_pc[spp*72 + 16*scg + 8] = p1;
    }
    __syncthreads();
    // issue next tile's loads (hide HBM latency under phase1+phase2)
    if (tile + 1 < tpc){
      const int n1 = (ch * tpc + tile + 1) * NT;
      const float* ga = xb + (size_t)rr * N_POS + n1 + 16*pg;
      fa0 = *(const float4*)ga;       fa1 = *(const float4*)(ga + 4);
      fa2 = *(const float4*)(ga + 8); fa3 = *(const float4*)(ga + 12);
      const float* gb = xb + (size_t)(16*scg) * N_POS + n1 + spp;
      #pragma unroll
      for (int i = 0; i < 16; ++i) v[i] = gb[(size_t)i * N_POS];
    }
    // phase1: S[pos][hd] -> E=exp -> es[hd][pos]
    #pragma unroll
    for (int ip = 0; ip < 2; ++ip){
      const int pt = pth + 4*ip;
      bf16x8 af0 = *(const bf16x8*)&xs_pc[(16*pt + lm)*72 + 8*lg];        // c 0..31
      bf16x8 af1 = *(const bf16x8*)&xs_pc[(16*pt + lm)*72 + 32 + 8*lg];   // c 32..63
      #pragma unroll
      for (int i = 0; i < 4; ++i){
        f32x4 s = (f32x4){0.f,0.f,0.f,0.f};
        s = __builtin_amdgcn_mfma_f32_16x16x32_bf16(af0, wkf[i][0], s, 0,0,0);
        s = __builtin_amdgcn_mfma_f32_16x16x32_bf16(af1, wkf[i][1], s, 0,0,0);
        // lane: pos = 16pt+4lg+r, hd = 16(ht0+i)+lm
        float e0 = __expf(s[0]), e1 = __expf(s[1]);
        float e2 = __expf(s[2]), e3 = __expf(s[3]);
        uint2 pk; pk.x = packbf(e0,e1); pk.y = packbf(e2,e3);
        *(uint2*)&es[(16*(ht0+i) + lm)*136 + 16*pt + 4*lg] = pk;
      }
    }
    __syncthreads();
    // phase2: wave w8 owns hd rows 16w8..16w8+15; K = 128 pos in 4 chunks
    __builtin_amdgcn_s_setprio(1);
    #pragma unroll
    for (int kk = 0; kk < 4; ++kk){
      bf16x8 ea = *(const bf16x8*)&es[(16*w8 + lm)*136 + 32*kk + 8*lg];
      bf16x8 xbf[4];
      #pragma unroll
      for (int n = 0; n < 4; ++n)
        xbf[n] = *(const bf16x8*)&xs_cp[(16*n + lm)*136 + 32*kk + 8*lg];
      #pragma unroll
      for (int n = 0; n < 4; ++n)
        acc[n] = __builtin_amdgcn_mfma_f32_16x16x32_bf16(ea, xbf[n], acc[n], 0,0,0);
      zac = __builtin_amdgcn_mfma_f32_16x16x32_bf16(ea, ones, zac, 0,0,0);
    }
    __builtin_amdgcn_s_setprio(0);
  }

  // epilogue: D-layout row hd = 16w8+4lg+r, col c = 16n+lm
  float* pa = pA + (size_t)blockIdx.x * 8192;
  const int hd0 = 16*w8 + 4*lg;
  #pragma unroll
  for (int n = 0; n < 4; ++n)
    #pragma unroll
    for (int r = 0; r < 4; ++r)
      pa[(size_t)(hd0 + r)*64 + 16*n + lm] = acc[n][r];
  if (lm == 0){
    #pragma unroll
    for (int r = 0; r < 4; ++r)
      pZ[(size_t)blockIdx.x * 128 + hd0 + r] = zac[r];
  }
}

// ---------------------------------------------------------------------------
// kernR1: parallel reduce of partials. grid 64 = 8 batches x 8 slices.
// ---------------------------------------------------------------------------
__global__ __launch_bounds__(256) void kernR1(
    const float* __restrict__ pA, const float* __restrict__ pZ,
    float* __restrict__ Ar, float* __restrict__ Zr, int nch)
{
  const int b = blockIdx.x >> 3, s = blockIdx.x & 7;
  const int off = s * 1024 + threadIdx.x * 4;
  float4 a = make_float4(0.f, 0.f, 0.f, 0.f);
  for (int ch = 0; ch < nch; ++ch){
    float4 v = *(const float4*)&pA[(size_t)(b * nch + ch) * 8192 + off];
    a.x += v.x; a.y += v.y; a.z += v.z; a.w += v.w;
  }
  *(float4*)&Ar[(size_t)b * 8192 + off] = a;
  if (s == 0 && threadIdx.x < 128){
    float z = 0.f;
    for (int ch = 0; ch < nch; ++ch) z += pZ[(size_t)(b * nch + ch) * 128 + threadIdx.x];
    Zr[b * 128 + threadIdx.x] = z;
  }
}

// ---------------------------------------------------------------------------
// kernCM (fused R2+M): per batch: ctx -> T -> M  (identical to R5)
// ---------------------------------------------------------------------------
__global__ __launch_bounds__(256) void kernCM(
    const float* __restrict__ Ar, const float* __restrict__ Zr,
    const float* __restrict__ w_qkv, const float* __restrict__ w_out,
    float* __restrict__ M)
{
  __shared__ float A[128 * 65];
  __shared__ float Z[128];
  __shared__ float cs[128 * 33];
  __shared__ float T[64 * 129];
  const int b = blockIdx.x, t = threadIdx.x;

  #pragma unroll
  for (int k = 0; k < 32; ++k){
    int i = t + 256 * k;
    A[(i >> 6) * 65 + (i & 63)] = Ar[(size_t)b * 8192 + i];
  }
  if (t < 128) Z[t] = Zr[b * 128 + t];
  __syncthreads();

  {
    const int hd = t & 127, h = hd >> 5, e0 = (t >> 7) * 16;
    const float rz = 1.0f / Z[hd];
    for (int je = 0; je < 16; ++je){
      int e = e0 + je;
      const float* wv = w_qkv + (size_t)(256 + 32 * h + e) * 64;   // Wv row
      float a = 0.f;
      #pragma unroll
      for (int c = 0; c < 64; ++c) a = fmaf(A[hd * 65 + c], wv[c], a);
      cs[hd * 33 + e] = a * rz;
    }
  }
  __syncthreads();

  const int o = t & 63, g = t >> 6;
  for (int jh = 0; jh < 32; ++jh){
    int hd = 32 * g + jh;
    const float* wo = w_out + (size_t)o * 128 + 32 * g;
    float a = 0.f;
    #pragma unroll
    for (int e = 0; e < 32; ++e) a = fmaf(wo[e], cs[hd * 33 + e], a);
    T[o * 129 + hd] = a;
  }
  __syncthreads();

  const int c0 = 16 * g;
  float m[16];
  #pragma unroll
  for (int j = 0; j < 16; ++j) m[j] = 0.f;
  for (int hd = 0; hd < 128; ++hd){
    float tv = T[o * 129 + hd];
    const float* wq = w_qkv + (size_t)hd * 64 + c0;
    #pragma unroll
    for (int j = 0; j < 16; ++j) m[j] = fmaf(tv, wq[j], m[j]);
  }
  #pragma unroll
  for (int j = 0; j < 16; ++j) M[(size_t)b * 4096 + o * 64 + c0 + j] = m[j];
}

// ---------------------------------------------------------------------------
// kernO (MFMA): per block: out[64, 256-pos tile] = M_b * x + b_out.
// (identical to R5)
// ---------------------------------------------------------------------------
__global__ __launch_bounds__(256, 4) void kernO(
    const float* __restrict__ x, const float* __restrict__ M,
    const float* __restrict__ b_out, float* __restrict__ out)
{
  __shared__ __align__(16) uint16_t xs[256 * 72];   // [pos][c], 36 KB

  const int t  = threadIdx.x;
  const int wv = t >> 6;
  const int l  = t & 63;
  const int lm = l & 15;
  const int lg = l >> 4;

  const int b  = blockIdx.x / 320;
  const int p0 = (blockIdx.x % 320) * 256;
  const float* xb = x + (size_t)b * 64 * N_POS + p0;

  // B-fragments of M: mb[ot][kk] -> lane holds M[16ot+lm][32kk+8lg+j]
  const float* Mb = M + (size_t)b * 4096;
  bf16x8 mb[4][2];
  float bias[4];
  #pragma unroll
  for (int ot = 0; ot < 4; ++ot){
    bias[ot] = b_out[16*ot + lm];
    #pragma unroll
    for (int kk = 0; kk < 2; ++kk){
      const float* mp = Mb + (size_t)(16*ot + lm)*64 + 32*kk + 8*lg;
      float4 m0 = *(const float4*)mp;
      float4 m1 = *(const float4*)(mp + 4);
      bf16x8 f;
      f[0]=bf16of(m0.x); f[1]=bf16of(m0.y); f[2]=bf16of(m0.z); f[3]=bf16of(m0.w);
      f[4]=bf16of(m1.x); f[5]=bf16of(m1.y); f[6]=bf16of(m1.z); f[7]=bf16of(m1.w);
      mb[ot][kk] = f;
    }
  }

  // stage xs[pos][c]: thread = one pos; per c coalesced across lanes
  #pragma unroll
  for (int cc = 0; cc < 8; ++cc){
    float v[8];
    #pragma unroll
    for (int j = 0; j < 8; ++j)
      v[j] = xb[(size_t)(8*cc + j) * N_POS + t];
    uint4 u;
    u.x = packbf(v[0],v[1]); u.y = packbf(v[2],v[3]);
    u.z = packbf(v[4],v[5]); u.w = packbf(v[6],v[7]);
    *(uint4*)&xs[t*72 + 8*cc] = u;
  }
  __syncthreads();

  float* ob = out + (size_t)b * 64 * N_POS + p0;

  // wave wv: pos-tiles 4wv .. 4wv+3
  #pragma unroll
  for (int ip = 0; ip < 4; ++ip){
    const int pt = 4*wv + ip;
    bf16x8 af0 = *(const bf16x8*)&xs[(16*pt + lm)*72 + 8*lg];        // c 0..31
    bf16x8 af1 = *(const bf16x8*)&xs[(16*pt + lm)*72 + 32 + 8*lg];   // c 32..63
    #pragma unroll
    for (int ot = 0; ot < 4; ++ot){
      f32x4 d = (f32x4){0.f,0.f,0.f,0.f};
      d = __builtin_amdgcn_mfma_f32_16x16x32_bf16(af0, mb[ot][0], d, 0,0,0);
      d = __builtin_amdgcn_mfma_f32_16x16x32_bf16(af1, mb[ot][1], d, 0,0,0);
      // lane: o = 16ot+lm, pos = 16pt + 4lg + r (r=0..3 contiguous)
      float4 st = make_float4(d[0]+bias[ot], d[1]+bias[ot],
                              d[2]+bias[ot], d[3]+bias[ot]);
      *(float4*)&ob[(size_t)(16*ot + lm) * N_POS + 16*pt + 4*lg] = st;
    }
  }
}

// ---------------------------------------------------------------------------
extern "C" void kernel_launch(void* const* d_in, const int* in_sizes, int n_in,
                              void* d_out, int out_size, void* d_ws, size_t ws_size,
                              hipStream_t stream)
{
  const float* x     = (const float*)d_in[0];
  const float* w_qkv = (const float*)d_in[1];
  const float* w_out = (const float*)d_in[2];
  const float* b_out = (const float*)d_in[3];
  float* out = (float*)d_out;
  float* ws  = (float*)d_ws;

  static const int cand[] = {64, 40, 32, 20, 16, 10, 8, 5, 4, 2, 1};
  int nch = 1;
  for (int i = 0; i < 11; ++i){
    size_t need = ((size_t)8 * cand[i] * (8192 + 128)
                   + 8 * 8192 + 8 * 128 + (size_t)8 * 4096) * 4;
    if (need <= ws_size){ nch = cand[i]; break; }
  }
  const int tpc = TILES / nch;

  float* pA  = ws;
  float* pZ  = pA + (size_t)8 * nch * 8192;
  float* Ar  = pZ + (size_t)8 * nch * 128;
  float* Zr  = Ar + (size_t)8 * 8192;
  float* M   = Zr + (size_t)8 * 128;

  // R6 instrumentation: kernA launched 3x (idempotent overwrite of pA/pZ).
  // kernA_dur = (dur_R6 - dur_R5) / 2.
  kernA<<<8 * nch, 512, 0, stream>>>(x, w_qkv, pA, pZ, nch, tpc);
  kernA<<<8 * nch, 512, 0, stream>>>(x, w_qkv, pA, pZ, nch, tpc);
  kernA<<<8 * nch, 512, 0, stream>>>(x, w_qkv, pA, pZ, nch, tpc);
  kernR1<<<64,     256, 0, stream>>>(pA, pZ, Ar, Zr, nch);
  kernCM<<<8,      256, 0, stream>>>(Ar, Zr, w_qkv, w_out, M);
  kernO<<<2560,    256, 0, stream>>>(x, M, b_out, out);
}

// Round 8
// 231.131 us; speedup vs baseline: 1.2714x; 1.2714x over previous
//
#include <hip/hip_runtime.h>
#include <stdint.h>

// LinearAttention. R7: kernO -> LDS-free direct-fragment GEMM (single change
// vs R5; kernA/R1/CM identical). Measured R6: kernA ~= 45us; kernO est 90-120.
// Math: final[b,o,n] = sum_c M_b[o,c] x[b,c,n] + b_out[o]
//   M_b = W_out * blockdiag_h(ctx_h^T) * W_q
//   ctx[hd][e] = (1/Z[hd]) sum_c A[hd][c] Wv[32h+e][c]
//   A[hd][c]   = sum_n exp(k[hd,n]) x[c,n],  Z[hd] = sum_n exp(k[hd,n])
//   k[hd,n]    = sum_c Wk[hd][c] x[c,n]   (k ~ N(0,0.4^2): exp fp32-safe)

#define N_POS 81920   // 80*1024
#define NT    128     // positions per kernA tile
#define TILES 640     // tiles per batch

typedef short bf16x8 __attribute__((ext_vector_type(8)));
typedef float f32x4  __attribute__((ext_vector_type(4)));

__device__ __forceinline__ uint32_t packbf(float lo, float hi){
  uint32_t a = __float_as_uint(lo), b = __float_as_uint(hi);
  a = (a + 0x8000u) >> 16;
  b = (b + 0x8000u) & 0xffff0000u;
  return a | b;
}
__device__ __forceinline__ short bf16of(float v){
  return (short)((__float_as_uint(v) + 0x8000u) >> 16);
}

// ---------------------------------------------------------------------------
// kernA: per (batch, chunk): partial A[128][64], Z[128] via MFMA. (R5)
// ---------------------------------------------------------------------------
__global__ __launch_bounds__(512, 4) void kernA(
    const float* __restrict__ x, const float* __restrict__ w,
    float* __restrict__ pA, float* __restrict__ pZ, int nch, int tpc)
{
  __shared__ __align__(16) uint16_t xs_cp[64 * 136];   // [c][pos]
  __shared__ __align__(16) uint16_t xs_pc[128 * 72];   // [pos][c]
  __shared__ __align__(16) uint16_t es[128 * 136];     // [hd][pos]

  const int t  = threadIdx.x;
  const int w8 = t >> 6;     // wave 0..7
  const int l  = t & 63;
  const int lm = l & 15;
  const int lg = l >> 4;

  const int b  = blockIdx.x / nch;
  const int ch = blockIdx.x % nch;
  const float* xb = x + (size_t)b * 64 * N_POS;

  const int rr  = t >> 3;        // xs_cp: c row 0..63
  const int pg  = t & 7;         // xs_cp: 16-pos group
  const int spp = t & 127;       // xs_pc: pos
  const int scg = t >> 7;        // xs_pc: c-group (16 c)

  const int pth = w8 & 3;
  const int ht0 = (w8 >> 2) * 4;

  bf16x8 wkf[4][2];
  #pragma unroll
  for (int i = 0; i < 4; ++i)
    #pragma unroll
    for (int kk = 0; kk < 2; ++kk){
      const float* wp = w + (size_t)(128 + 16*(ht0+i) + lm) * 64 + 32*kk + 8*lg;
      float4 w0 = *(const float4*)wp;
      float4 w1 = *(const float4*)(wp + 4);
      bf16x8 f;
      f[0]=bf16of(w0.x); f[1]=bf16of(w0.y); f[2]=bf16of(w0.z); f[3]=bf16of(w0.w);
      f[4]=bf16of(w1.x); f[5]=bf16of(w1.y); f[6]=bf16of(w1.z); f[7]=bf16of(w1.w);
      wkf[i][kk] = f;
    }

  bf16x8 ones;
  #pragma unroll
  for (int j = 0; j < 8; ++j) ones[j] = (short)0x3F80;   // bf16 1.0

  f32x4 acc[4], zac;
  zac = (f32x4){0.f,0.f,0.f,0.f};
  #pragma unroll
  for (int n = 0; n < 4; ++n) acc[n] = (f32x4){0.f,0.f,0.f,0.f};

  float4 fa0, fa1, fa2, fa3;
  float v[16];
  {
    const int n0 = (ch * tpc) * NT;
    const float* ga = xb + (size_t)rr * N_POS + n0 + 16*pg;
    fa0 = *(const float4*)ga;       fa1 = *(const float4*)(ga + 4);
    fa2 = *(const float4*)(ga + 8); fa3 = *(const float4*)(ga + 12);
    const float* gb = xb + (size_t)(16*scg) * N_POS + n0 + spp;
    #pragma unroll
    for (int i = 0; i < 16; ++i) v[i] = gb[(size_t)i * N_POS];
  }

  for (int tile = 0; tile < tpc; ++tile){
    __syncthreads();
    {
      uint4 u0, u1;
      u0.x = packbf(fa0.x,fa0.y); u0.y = packbf(fa0.z,fa0.w);
      u0.z = packbf(fa1.x,fa1.y); u0.w = packbf(fa1.z,fa1.w);
      u1.x = packbf(fa2.x,fa2.y); u1.y = packbf(fa2.z,fa2.w);
      u1.z = packbf(fa3.x,fa3.y); u1.w = packbf(fa3.z,fa3.w);
      *(uint4*)&xs_cp[rr*136 + 16*pg]     = u0;
      *(uint4*)&xs_cp[rr*136 + 16*pg + 8] = u1;
      uint4 p0, p1;
      p0.x = packbf(v[0],v[1]);   p0.y = packbf(v[2],v[3]);
      p0.z = packbf(v[4],v[5]);   p0.w = packbf(v[6],v[7]);
      p1.x = packbf(v[8],v[9]);   p1.y = packbf(v[10],v[11]);
      p1.z = packbf(v[12],v[13]); p1.w = packbf(v[14],v[15]);
      *(uint4*)&xs_pc[spp*72 + 16*scg]     = p0;
      *(uint4*)&xs_pc[spp*72 + 16*scg + 8] = p1;
    }
    __syncthreads();
    if (tile + 1 < tpc){
      const int n1 = (ch * tpc + tile + 1) * NT;
      const float* ga = xb + (size_t)rr * N_POS + n1 + 16*pg;
      fa0 = *(const float4*)ga;       fa1 = *(const float4*)(ga + 4);
      fa2 = *(const float4*)(ga + 8); fa3 = *(const float4*)(ga + 12);
      const float* gb = xb + (size_t)(16*scg) * N_POS + n1 + spp;
      #pragma unroll
      for (int i = 0; i < 16; ++i) v[i] = gb[(size_t)i * N_POS];
    }
    #pragma unroll
    for (int ip = 0; ip < 2; ++ip){
      const int pt = pth + 4*ip;
      bf16x8 af0 = *(const bf16x8*)&xs_pc[(16*pt + lm)*72 + 8*lg];
      bf16x8 af1 = *(const bf16x8*)&xs_pc[(16*pt + lm)*72 + 32 + 8*lg];
      #pragma unroll
      for (int i = 0; i < 4; ++i){
        f32x4 s = (f32x4){0.f,0.f,0.f,0.f};
        s = __builtin_amdgcn_mfma_f32_16x16x32_bf16(af0, wkf[i][0], s, 0,0,0);
        s = __builtin_amdgcn_mfma_f32_16x16x32_bf16(af1, wkf[i][1], s, 0,0,0);
        float e0 = __expf(s[0]), e1 = __expf(s[1]);
        float e2 = __expf(s[2]), e3 = __expf(s[3]);
        uint2 pk; pk.x = packbf(e0,e1); pk.y = packbf(e2,e3);
        *(uint2*)&es[(16*(ht0+i) + lm)*136 + 16*pt + 4*lg] = pk;
      }
    }
    __syncthreads();
    __builtin_amdgcn_s_setprio(1);
    #pragma unroll
    for (int kk = 0; kk < 4; ++kk){
      bf16x8 ea = *(const bf16x8*)&es[(16*w8 + lm)*136 + 32*kk + 8*lg];
      bf16x8 xbf[4];
      #pragma unroll
      for (int n = 0; n < 4; ++n)
        xbf[n] = *(const bf16x8*)&xs_cp[(16*n + lm)*136 + 32*kk + 8*lg];
      #pragma unroll
      for (int n = 0; n < 4; ++n)
        acc[n] = __builtin_amdgcn_mfma_f32_16x16x32_bf16(ea, xbf[n], acc[n], 0,0,0);
      zac = __builtin_amdgcn_mfma_f32_16x16x32_bf16(ea, ones, zac, 0,0,0);
    }
    __builtin_amdgcn_s_setprio(0);
  }

  float* pa = pA + (size_t)blockIdx.x * 8192;
  const int hd0 = 16*w8 + 4*lg;
  #pragma unroll
  for (int n = 0; n < 4; ++n)
    #pragma unroll
    for (int r = 0; r < 4; ++r)
      pa[(size_t)(hd0 + r)*64 + 16*n + lm] = acc[n][r];
  if (lm == 0){
    #pragma unroll
    for (int r = 0; r < 4; ++r)
      pZ[(size_t)blockIdx.x * 128 + hd0 + r] = zac[r];
  }
}

// ---------------------------------------------------------------------------
// kernR1: parallel reduce of partials. grid 64 = 8 batches x 8 slices.
// ---------------------------------------------------------------------------
__global__ __launch_bounds__(256) void kernR1(
    const float* __restrict__ pA, const float* __restrict__ pZ,
    float* __restrict__ Ar, float* __restrict__ Zr, int nch)
{
  const int b = blockIdx.x >> 3, s = blockIdx.x & 7;
  const int off = s * 1024 + threadIdx.x * 4;
  float4 a = make_float4(0.f, 0.f, 0.f, 0.f);
  for (int ch = 0; ch < nch; ++ch){
    float4 v = *(const float4*)&pA[(size_t)(b * nch + ch) * 8192 + off];
    a.x += v.x; a.y += v.y; a.z += v.z; a.w += v.w;
  }
  *(float4*)&Ar[(size_t)b * 8192 + off] = a;
  if (s == 0 && threadIdx.x < 128){
    float z = 0.f;
    for (int ch = 0; ch < nch; ++ch) z += pZ[(size_t)(b * nch + ch) * 128 + threadIdx.x];
    Zr[b * 128 + threadIdx.x] = z;
  }
}

// ---------------------------------------------------------------------------
// kernCM (fused R2+M): per batch: ctx -> T -> M  (R5)
// ---------------------------------------------------------------------------
__global__ __launch_bounds__(256) void kernCM(
    const float* __restrict__ Ar, const float* __restrict__ Zr,
    const float* __restrict__ w_qkv, const float* __restrict__ w_out,
    float* __restrict__ M)
{
  __shared__ float A[128 * 65];
  __shared__ float Z[128];
  __shared__ float cs[128 * 33];
  __shared__ float T[64 * 129];
  const int b = blockIdx.x, t = threadIdx.x;

  #pragma unroll
  for (int k = 0; k < 32; ++k){
    int i = t + 256 * k;
    A[(i >> 6) * 65 + (i & 63)] = Ar[(size_t)b * 8192 + i];
  }
  if (t < 128) Z[t] = Zr[b * 128 + t];
  __syncthreads();

  {
    const int hd = t & 127, h = hd >> 5, e0 = (t >> 7) * 16;
    const float rz = 1.0f / Z[hd];
    for (int je = 0; je < 16; ++je){
      int e = e0 + je;
      const float* wv = w_qkv + (size_t)(256 + 32 * h + e) * 64;   // Wv row
      float a = 0.f;
      #pragma unroll
      for (int c = 0; c < 64; ++c) a = fmaf(A[hd * 65 + c], wv[c], a);
      cs[hd * 33 + e] = a * rz;
    }
  }
  __syncthreads();

  const int o = t & 63, g = t >> 6;
  for (int jh = 0; jh < 32; ++jh){
    int hd = 32 * g + jh;
    const float* wo = w_out + (size_t)o * 128 + 32 * g;
    float a = 0.f;
    #pragma unroll
    for (int e = 0; e < 32; ++e) a = fmaf(wo[e], cs[hd * 33 + e], a);
    T[o * 129 + hd] = a;
  }
  __syncthreads();

  const int c0 = 16 * g;
  float m[16];
  #pragma unroll
  for (int j = 0; j < 16; ++j) m[j] = 0.f;
  for (int hd = 0; hd < 128; ++hd){
    float tv = T[o * 129 + hd];
    const float* wq = w_qkv + (size_t)hd * 64 + c0;
    #pragma unroll
    for (int j = 0; j < 16; ++j) m[j] = fmaf(tv, wq[j], m[j]);
  }
  #pragma unroll
  for (int j = 0; j < 16; ++j) M[(size_t)b * 4096 + o * 64 + c0 + j] = m[j];
}

// ---------------------------------------------------------------------------
// kernO (R7): LDS-free. A-fragments loaded directly from global:
//   af[j] = x[c=8lg+j][p0+16pt+lm]  (per instr: 4 x 64B segments, no overfetch)
// 16 loads in flight per fragment-pair, one wait, no barrier, no LDS.
// ---------------------------------------------------------------------------
__global__ __launch_bounds__(256, 4) void kernO(
    const float* __restrict__ x, const float* __restrict__ M,
    const float* __restrict__ b_out, float* __restrict__ out)
{
  const int t  = threadIdx.x;
  const int wv = t >> 6;
  const int l  = t & 63;
  const int lm = l & 15;
  const int lg = l >> 4;

  const int b  = blockIdx.x / 320;
  const int p0 = (blockIdx.x % 320) * 256;
  const float* xb = x + (size_t)b * 64 * N_POS + p0;

  // B-fragments of M: mb[ot][kk] -> lane holds M[16ot+lm][32kk+8lg+j]
  const float* Mb = M + (size_t)b * 4096;
  bf16x8 mb[4][2];
  float bias[4];
  #pragma unroll
  for (int ot = 0; ot < 4; ++ot){
    bias[ot] = b_out[16*ot + lm];
    #pragma unroll
    for (int kk = 0; kk < 2; ++kk){
      const float* mp = Mb + (size_t)(16*ot + lm)*64 + 32*kk + 8*lg;
      float4 m0 = *(const float4*)mp;
      float4 m1 = *(const float4*)(mp + 4);
      bf16x8 f;
      f[0]=bf16of(m0.x); f[1]=bf16of(m0.y); f[2]=bf16of(m0.z); f[3]=bf16of(m0.w);
      f[4]=bf16of(m1.x); f[5]=bf16of(m1.y); f[6]=bf16of(m1.z); f[7]=bf16of(m1.w);
      mb[ot][kk] = f;
    }
  }

  float* ob = out + (size_t)b * 64 * N_POS + p0;

  // wave wv: pos-tiles 4wv .. 4wv+3
  #pragma unroll
  for (int ip = 0; ip < 4; ++ip){
    const int pt = 4*wv + ip;
    const float* gx = xb + 16*pt + lm;
    float a0[8], a1[8];
    #pragma unroll
    for (int j = 0; j < 8; ++j){
      a0[j] = gx[(size_t)(8*lg + j) * N_POS];        // c 0..31 slice
      a1[j] = gx[(size_t)(32 + 8*lg + j) * N_POS];   // c 32..63 slice
    }
    bf16x8 af0, af1;
    #pragma unroll
    for (int j = 0; j < 8; ++j){
      af0[j] = bf16of(a0[j]);
      af1[j] = bf16of(a1[j]);
    }
    #pragma unroll
    for (int ot = 0; ot < 4; ++ot){
      f32x4 d = (f32x4){0.f,0.f,0.f,0.f};
      d = __builtin_amdgcn_mfma_f32_16x16x32_bf16(af0, mb[ot][0], d, 0,0,0);
      d = __builtin_amdgcn_mfma_f32_16x16x32_bf16(af1, mb[ot][1], d, 0,0,0);
      // lane: o = 16ot+lm, pos = 16pt + 4lg + r (r=0..3 contiguous)
      float4 st = make_float4(d[0]+bias[ot], d[1]+bias[ot],
                              d[2]+bias[ot], d[3]+bias[ot]);
      *(float4*)&ob[(size_t)(16*ot + lm) * N_POS + 16*pt + 4*lg] = st;
    }
  }
}

// ---------------------------------------------------------------------------
extern "C" void kernel_launch(void* const* d_in, const int* in_sizes, int n_in,
                              void* d_out, int out_size, void* d_ws, size_t ws_size,
                              hipStream_t stream)
{
  const float* x     = (const float*)d_in[0];
  const float* w_qkv = (const float*)d_in[1];
  const float* w_out = (const float*)d_in[2];
  const float* b_out = (const float*)d_in[3];
  float* out = (float*)d_out;
  float* ws  = (float*)d_ws;

  static const int cand[] = {64, 40, 32, 20, 16, 10, 8, 5, 4, 2, 1};
  int nch = 1;
  for (int i = 0; i < 11; ++i){
    size_t need = ((size_t)8 * cand[i] * (8192 + 128)
                   + 8 * 8192 + 8 * 128 + (size_t)8 * 4096) * 4;
    if (need <= ws_size){ nch = cand[i]; break; }
  }
  const int tpc = TILES / nch;

  float* pA  = ws;
  float* pZ  = pA + (size_t)8 * nch * 8192;
  float* Ar  = pZ + (size_t)8 * nch * 128;
  float* Zr  = Ar + (size_t)8 * 8192;
  float* M   = Zr + (size_t)8 * 128;

  kernA<<<8 * nch, 512, 0, stream>>>(x, w_qkv, pA, pZ, nch, tpc);
  kernR1<<<64,     256, 0, stream>>>(pA, pZ, Ar, Zr, nch);
  kernCM<<<8,      256, 0, stream>>>(Ar, Zr, w_qkv, w_out, M);
  kernO<<<2560,    256, 0, stream>>>(x, M, b_out, out);
}

// Round 9
// 209.381 us; speedup vs baseline: 1.4034x; 1.1039x over previous
//
#include <hip/hip_runtime.h>
#include <stdint.h>

// LinearAttention. R9: kernO v4 — staged LDS (R5 pattern) + double-buffered
// cross-tile pipeline (5 tiles/block, 1 barrier/tile, T14 issue-early).
// kernA/R1/CM identical to R5/R7.
// Math: final[b,o,n] = sum_c M_b[o,c] x[b,c,n] + b_out[o]
//   M_b = W_out * blockdiag_h(ctx_h^T) * W_q
//   ctx[hd][e] = (1/Z[hd]) sum_c A[hd][c] Wv[32h+e][c]
//   A[hd][c]   = sum_n exp(k[hd,n]) x[c,n],  Z[hd] = sum_n exp(k[hd,n])
//   k[hd,n]    = sum_c Wk[hd][c] x[c,n]   (k ~ N(0,0.4^2): exp fp32-safe)

#define N_POS 81920   // 80*1024
#define NT    128     // positions per kernA tile
#define TILES 640     // tiles per batch

typedef short bf16x8 __attribute__((ext_vector_type(8)));
typedef float f32x4  __attribute__((ext_vector_type(4)));

__device__ __forceinline__ uint32_t packbf(float lo, float hi){
  uint32_t a = __float_as_uint(lo), b = __float_as_uint(hi);
  a = (a + 0x8000u) >> 16;
  b = (b + 0x8000u) & 0xffff0000u;
  return a | b;
}
__device__ __forceinline__ short bf16of(float v){
  return (short)((__float_as_uint(v) + 0x8000u) >> 16);
}

// ---------------------------------------------------------------------------
// kernA: per (batch, chunk): partial A[128][64], Z[128] via MFMA. (R5)
// ---------------------------------------------------------------------------
__global__ __launch_bounds__(512, 4) void kernA(
    const float* __restrict__ x, const float* __restrict__ w,
    float* __restrict__ pA, float* __restrict__ pZ, int nch, int tpc)
{
  __shared__ __align__(16) uint16_t xs_cp[64 * 136];   // [c][pos]
  __shared__ __align__(16) uint16_t xs_pc[128 * 72];   // [pos][c]
  __shared__ __align__(16) uint16_t es[128 * 136];     // [hd][pos]

  const int t  = threadIdx.x;
  const int w8 = t >> 6;     // wave 0..7
  const int l  = t & 63;
  const int lm = l & 15;
  const int lg = l >> 4;

  const int b  = blockIdx.x / nch;
  const int ch = blockIdx.x % nch;
  const float* xb = x + (size_t)b * 64 * N_POS;

  const int rr  = t >> 3;        // xs_cp: c row 0..63
  const int pg  = t & 7;         // xs_cp: 16-pos group
  const int spp = t & 127;       // xs_pc: pos
  const int scg = t >> 7;        // xs_pc: c-group (16 c)

  const int pth = w8 & 3;
  const int ht0 = (w8 >> 2) * 4;

  bf16x8 wkf[4][2];
  #pragma unroll
  for (int i = 0; i < 4; ++i)
    #pragma unroll
    for (int kk = 0; kk < 2; ++kk){
      const float* wp = w + (size_t)(128 + 16*(ht0+i) + lm) * 64 + 32*kk + 8*lg;
      float4 w0 = *(const float4*)wp;
      float4 w1 = *(const float4*)(wp + 4);
      bf16x8 f;
      f[0]=bf16of(w0.x); f[1]=bf16of(w0.y); f[2]=bf16of(w0.z); f[3]=bf16of(w0.w);
      f[4]=bf16of(w1.x); f[5]=bf16of(w1.y); f[6]=bf16of(w1.z); f[7]=bf16of(w1.w);
      wkf[i][kk] = f;
    }

  bf16x8 ones;
  #pragma unroll
  for (int j = 0; j < 8; ++j) ones[j] = (short)0x3F80;   // bf16 1.0

  f32x4 acc[4], zac;
  zac = (f32x4){0.f,0.f,0.f,0.f};
  #pragma unroll
  for (int n = 0; n < 4; ++n) acc[n] = (f32x4){0.f,0.f,0.f,0.f};

  float4 fa0, fa1, fa2, fa3;
  float v[16];
  {
    const int n0 = (ch * tpc) * NT;
    const float* ga = xb + (size_t)rr * N_POS + n0 + 16*pg;
    fa0 = *(const float4*)ga;       fa1 = *(const float4*)(ga + 4);
    fa2 = *(const float4*)(ga + 8); fa3 = *(const float4*)(ga + 12);
    const float* gb = xb + (size_t)(16*scg) * N_POS + n0 + spp;
    #pragma unroll
    for (int i = 0; i < 16; ++i) v[i] = gb[(size_t)i * N_POS];
  }

  for (int tile = 0; tile < tpc; ++tile){
    __syncthreads();
    {
      uint4 u0, u1;
      u0.x = packbf(fa0.x,fa0.y); u0.y = packbf(fa0.z,fa0.w);
      u0.z = packbf(fa1.x,fa1.y); u0.w = packbf(fa1.z,fa1.w);
      u1.x = packbf(fa2.x,fa2.y); u1.y = packbf(fa2.z,fa2.w);
      u1.z = packbf(fa3.x,fa3.y); u1.w = packbf(fa3.z,fa3.w);
      *(uint4*)&xs_cp[rr*136 + 16*pg]     = u0;
      *(uint4*)&xs_cp[rr*136 + 16*pg + 8] = u1;
      uint4 p0, p1;
      p0.x = packbf(v[0],v[1]);   p0.y = packbf(v[2],v[3]);
      p0.z = packbf(v[4],v[5]);   p0.w = packbf(v[6],v[7]);
      p1.x = packbf(v[8],v[9]);   p1.y = packbf(v[10],v[11]);
      p1.z = packbf(v[12],v[13]); p1.w = packbf(v[14],v[15]);
      *(uint4*)&xs_pc[spp*72 + 16*scg]     = p0;
      *(uint4*)&xs_pc[spp*72 + 16*scg + 8] = p1;
    }
    __syncthreads();
    if (tile + 1 < tpc){
      const int n1 = (ch * tpc + tile + 1) * NT;
      const float* ga = xb + (size_t)rr * N_POS + n1 + 16*pg;
      fa0 = *(const float4*)ga;       fa1 = *(const float4*)(ga + 4);
      fa2 = *(const float4*)(ga + 8); fa3 = *(const float4*)(ga + 12);
      const float* gb = xb + (size_t)(16*scg) * N_POS + n1 + spp;
      #pragma unroll
      for (int i = 0; i < 16; ++i) v[i] = gb[(size_t)i * N_POS];
    }
    #pragma unroll
    for (int ip = 0; ip < 2; ++ip){
      const int pt = pth + 4*ip;
      bf16x8 af0 = *(const bf16x8*)&xs_pc[(16*pt + lm)*72 + 8*lg];
      bf16x8 af1 = *(const bf16x8*)&xs_pc[(16*pt + lm)*72 + 32 + 8*lg];
      #pragma unroll
      for (int i = 0; i < 4; ++i){
        f32x4 s = (f32x4){0.f,0.f,0.f,0.f};
        s = __builtin_amdgcn_mfma_f32_16x16x32_bf16(af0, wkf[i][0], s, 0,0,0);
        s = __builtin_amdgcn_mfma_f32_16x16x32_bf16(af1, wkf[i][1], s, 0,0,0);
        float e0 = __expf(s[0]), e1 = __expf(s[1]);
        float e2 = __expf(s[2]), e3 = __expf(s[3]);
        uint2 pk; pk.x = packbf(e0,e1); pk.y = packbf(e2,e3);
        *(uint2*)&es[(16*(ht0+i) + lm)*136 + 16*pt + 4*lg] = pk;
      }
    }
    __syncthreads();
    __builtin_amdgcn_s_setprio(1);
    #pragma unroll
    for (int kk = 0; kk < 4; ++kk){
      bf16x8 ea = *(const bf16x8*)&es[(16*w8 + lm)*136 + 32*kk + 8*lg];
      bf16x8 xbf[4];
      #pragma unroll
      for (int n = 0; n < 4; ++n)
        xbf[n] = *(const bf16x8*)&xs_cp[(16*n + lm)*136 + 32*kk + 8*lg];
      #pragma unroll
      for (int n = 0; n < 4; ++n)
        acc[n] = __builtin_amdgcn_mfma_f32_16x16x32_bf16(ea, xbf[n], acc[n], 0,0,0);
      zac = __builtin_amdgcn_mfma_f32_16x16x32_bf16(ea, ones, zac, 0,0,0);
    }
    __builtin_amdgcn_s_setprio(0);
  }

  float* pa = pA + (size_t)blockIdx.x * 8192;
  const int hd0 = 16*w8 + 4*lg;
  #pragma unroll
  for (int n = 0; n < 4; ++n)
    #pragma unroll
    for (int r = 0; r < 4; ++r)
      pa[(size_t)(hd0 + r)*64 + 16*n + lm] = acc[n][r];
  if (lm == 0){
    #pragma unroll
    for (int r = 0; r < 4; ++r)
      pZ[(size_t)blockIdx.x * 128 + hd0 + r] = zac[r];
  }
}

// ---------------------------------------------------------------------------
// kernR1: parallel reduce of partials. grid 64 = 8 batches x 8 slices.
// ---------------------------------------------------------------------------
__global__ __launch_bounds__(256) void kernR1(
    const float* __restrict__ pA, const float* __restrict__ pZ,
    float* __restrict__ Ar, float* __restrict__ Zr, int nch)
{
  const int b = blockIdx.x >> 3, s = blockIdx.x & 7;
  const int off = s * 1024 + threadIdx.x * 4;
  float4 a = make_float4(0.f, 0.f, 0.f, 0.f);
  for (int ch = 0; ch < nch; ++ch){
    float4 v = *(const float4*)&pA[(size_t)(b * nch + ch) * 8192 + off];
    a.x += v.x; a.y += v.y; a.z += v.z; a.w += v.w;
  }
  *(float4*)&Ar[(size_t)b * 8192 + off] = a;
  if (s == 0 && threadIdx.x < 128){
    float z = 0.f;
    for (int ch = 0; ch < nch; ++ch) z += pZ[(size_t)(b * nch + ch) * 128 + threadIdx.x];
    Zr[b * 128 + threadIdx.x] = z;
  }
}

// ---------------------------------------------------------------------------
// kernCM (fused R2+M): per batch: ctx -> T -> M  (R5)
// ---------------------------------------------------------------------------
__global__ __launch_bounds__(256) void kernCM(
    const float* __restrict__ Ar, const float* __restrict__ Zr,
    const float* __restrict__ w_qkv, const float* __restrict__ w_out,
    float* __restrict__ M)
{
  __shared__ float A[128 * 65];
  __shared__ float Z[128];
  __shared__ float cs[128 * 33];
  __shared__ float T[64 * 129];
  const int b = blockIdx.x, t = threadIdx.x;

  #pragma unroll
  for (int k = 0; k < 32; ++k){
    int i = t + 256 * k;
    A[(i >> 6) * 65 + (i & 63)] = Ar[(size_t)b * 8192 + i];
  }
  if (t < 128) Z[t] = Zr[b * 128 + t];
  __syncthreads();

  {
    const int hd = t & 127, h = hd >> 5, e0 = (t >> 7) * 16;
    const float rz = 1.0f / Z[hd];
    for (int je = 0; je < 16; ++je){
      int e = e0 + je;
      const float* wv = w_qkv + (size_t)(256 + 32 * h + e) * 64;   // Wv row
      float a = 0.f;
      #pragma unroll
      for (int c = 0; c < 64; ++c) a = fmaf(A[hd * 65 + c], wv[c], a);
      cs[hd * 33 + e] = a * rz;
    }
  }
  __syncthreads();

  const int o = t & 63, g = t >> 6;
  for (int jh = 0; jh < 32; ++jh){
    int hd = 32 * g + jh;
    const float* wo = w_out + (size_t)o * 128 + 32 * g;
    float a = 0.f;
    #pragma unroll
    for (int e = 0; e < 32; ++e) a = fmaf(wo[e], cs[hd * 33 + e], a);
    T[o * 129 + hd] = a;
  }
  __syncthreads();

  const int c0 = 16 * g;
  float m[16];
  #pragma unroll
  for (int j = 0; j < 16; ++j) m[j] = 0.f;
  for (int hd = 0; hd < 128; ++hd){
    float tv = T[o * 129 + hd];
    const float* wq = w_qkv + (size_t)hd * 64 + c0;
    #pragma unroll
    for (int j = 0; j < 16; ++j) m[j] = fmaf(tv, wq[j], m[j]);
  }
  #pragma unroll
  for (int j = 0; j < 16; ++j) M[(size_t)b * 4096 + o * 64 + c0 + j] = m[j];
}

// ---------------------------------------------------------------------------
// kernO v4: grid 512 (8b x 64 groups), 5 tiles of 256 pos per block.
// Double-buffered LDS [pos][c] (2 x 36KB); per tile: issue next tile's 64
// coalesced loads (pack to 32 VGPRs), compute current (32 MFMA + 16 stores,
// hides load latency), write next buffer, ONE barrier.
// Race-freedom: tile-T writes hit the buffer last read at T-1; every wave
// passed tile-(T-1)'s barrier only after completing those reads.
// ---------------------------------------------------------------------------
__global__ __launch_bounds__(256, 2) void kernO(
    const float* __restrict__ x, const float* __restrict__ M,
    const float* __restrict__ b_out, float* __restrict__ out)
{
  __shared__ __align__(16) uint16_t xs[2][256 * 72];   // 72 KB

  const int t  = threadIdx.x;
  const int wv = t >> 6;
  const int l  = t & 63;
  const int lm = l & 15;
  const int lg = l >> 4;

  const int b  = blockIdx.x >> 6;          // batch
  const int tg = blockIdx.x & 63;          // 1280-pos group
  const float* xb = x   + (size_t)b * 64 * N_POS + tg * 1280;
  float*       ob = out + (size_t)b * 64 * N_POS + tg * 1280;

  // B-fragments of M: mb[ot][kk] -> lane holds M[16ot+lm][32kk+8lg+j]
  const float* Mb = M + (size_t)b * 4096;
  bf16x8 mb[4][2];
  float bias[4];
  #pragma unroll
  for (int ot = 0; ot < 4; ++ot){
    bias[ot] = b_out[16*ot + lm];
    #pragma unroll
    for (int kk = 0; kk < 2; ++kk){
      const float* mp = Mb + (size_t)(16*ot + lm)*64 + 32*kk + 8*lg;
      float4 m0 = *(const float4*)mp;
      float4 m1 = *(const float4*)(mp + 4);
      bf16x8 f;
      f[0]=bf16of(m0.x); f[1]=bf16of(m0.y); f[2]=bf16of(m0.z); f[3]=bf16of(m0.w);
      f[4]=bf16of(m1.x); f[5]=bf16of(m1.y); f[6]=bf16of(m1.z); f[7]=bf16of(m1.w);
      mb[ot][kk] = f;
    }
  }

  uint4 st[8];   // staged packed tile (32 VGPRs), static-indexed only

  // prologue: stage tile 0 into xs[0]
  #pragma unroll
  for (int cc = 0; cc < 8; ++cc){
    float v[8];
    #pragma unroll
    for (int j = 0; j < 8; ++j)
      v[j] = xb[(size_t)(8*cc + j) * N_POS + t];
    st[cc].x = packbf(v[0],v[1]); st[cc].y = packbf(v[2],v[3]);
    st[cc].z = packbf(v[4],v[5]); st[cc].w = packbf(v[6],v[7]);
  }
  #pragma unroll
  for (int cc = 0; cc < 8; ++cc)
    *(uint4*)&xs[0][t*72 + 8*cc] = st[cc];
  __syncthreads();

  for (int tile = 0; tile < 5; ++tile){
    const int cur = tile & 1;
    // T14: issue next tile's loads early (latency hides under compute+stores)
    if (tile < 4){
      const float* gn = xb + (tile + 1) * 256 + t;
      #pragma unroll
      for (int cc = 0; cc < 8; ++cc){
        float v[8];
        #pragma unroll
        for (int j = 0; j < 8; ++j)
          v[j] = gn[(size_t)(8*cc + j) * N_POS];
        st[cc].x = packbf(v[0],v[1]); st[cc].y = packbf(v[2],v[3]);
        st[cc].z = packbf(v[4],v[5]); st[cc].w = packbf(v[6],v[7]);
      }
    }
    // compute current tile from xs[cur]
    const int pp0 = tile * 256;
    #pragma unroll
    for (int ip = 0; ip < 4; ++ip){
      const int pt = 4*wv + ip;
      bf16x8 af0 = *(const bf16x8*)&xs[cur][(16*pt + lm)*72 + 8*lg];
      bf16x8 af1 = *(const bf16x8*)&xs[cur][(16*pt + lm)*72 + 32 + 8*lg];
      #pragma unroll
      for (int ot = 0; ot < 4; ++ot){
        f32x4 d = (f32x4){0.f,0.f,0.f,0.f};
        d = __builtin_amdgcn_mfma_f32_16x16x32_bf16(af0, mb[ot][0], d, 0,0,0);
        d = __builtin_amdgcn_mfma_f32_16x16x32_bf16(af1, mb[ot][1], d, 0,0,0);
        float4 stv = make_float4(d[0]+bias[ot], d[1]+bias[ot],
                                 d[2]+bias[ot], d[3]+bias[ot]);
        *(float4*)&ob[(size_t)(16*ot + lm) * N_POS + pp0 + 16*pt + 4*lg] = stv;
      }
    }
    // write next tile into the other buffer, single barrier
    if (tile < 4){
      #pragma unroll
      for (int cc = 0; cc < 8; ++cc)
        *(uint4*)&xs[cur ^ 1][t*72 + 8*cc] = st[cc];
      __syncthreads();
    }
  }
}

// ---------------------------------------------------------------------------
extern "C" void kernel_launch(void* const* d_in, const int* in_sizes, int n_in,
                              void* d_out, int out_size, void* d_ws, size_t ws_size,
                              hipStream_t stream)
{
  const float* x     = (const float*)d_in[0];
  const float* w_qkv = (const float*)d_in[1];
  const float* w_out = (const float*)d_in[2];
  const float* b_out = (const float*)d_in[3];
  float* out = (float*)d_out;
  float* ws  = (float*)d_ws;

  static const int cand[] = {64, 40, 32, 20, 16, 10, 8, 5, 4, 2, 1};
  int nch = 1;
  for (int i = 0; i < 11; ++i){
    size_t need = ((size_t)8 * cand[i] * (8192 + 128)
                   + 8 * 8192 + 8 * 128 + (size_t)8 * 4096) * 4;
    if (need <= ws_size){ nch = cand[i]; break; }
  }
  const int tpc = TILES / nch;

  float* pA  = ws;
  float* pZ  = pA + (size_t)8 * nch * 8192;
  float* Ar  = pZ + (size_t)8 * nch * 128;
  float* Zr  = Ar + (size_t)8 * 8192;
  float* M   = Zr + (size_t)8 * 128;

  kernA<<<8 * nch, 512, 0, stream>>>(x, w_qkv, pA, pZ, nch, tpc);
  kernR1<<<64,     256, 0, stream>>>(pA, pZ, Ar, Zr, nch);
  kernCM<<<8,      256, 0, stream>>>(Ar, Zr, w_qkv, w_out, M);
  kernO<<<512,     256, 0, stream>>>(x, M, b_out, out);
}